// Round 8
// baseline (174.474 us; speedup 1.0000x reference)
//
#include <hip/hip_runtime.h>

#define C_DIM 128
#define EPS 1e-5f
#define NBIN 784   // bins of 64 nodes (capacity; covers N <= 50176)
#define SBLK 2048  // edges per hist/sort block -> 313 blocks for E=640000

typedef __attribute__((ext_vector_type(8))) short short8;
typedef __attribute__((ext_vector_type(4))) float f32x4;

__device__ __forceinline__ unsigned bf16rn(float f) {
    unsigned u = __float_as_uint(f);
    return (u + 0x7fffu + ((u >> 16) & 1u)) >> 16;
}
__device__ __forceinline__ unsigned pack_bf16(float lo, float hi) {
    return bf16rn(lo) | (bf16rn(hi) << 16);
}
__device__ __forceinline__ float blo(unsigned u) { return __uint_as_float(u << 16); }
__device__ __forceinline__ float bhi(unsigned u) { return __uint_as_float(u & 0xffff0000u); }

// exclusive scan of LDS buf[0..NBIN) by ONE full wave (all 64 lanes must enter).
// If dumpb != 0, also writes dumpb[i]=exclusive prefix and dumpb[NBIN]=grand total.
__device__ __forceinline__ void wave_scan_excl_lds(unsigned* buf, int lane,
                                                   unsigned* dumpb) {
    const int CH = (NBIN + 63) / 64;  // 13
    unsigned v[CH];
    unsigned s = 0;
    int c0 = lane * CH;
#pragma unroll
    for (int k = 0; k < CH; k++) {
        int idx = c0 + k;
        v[k] = (idx < NBIN) ? buf[idx] : 0u;
        s += v[k];
    }
    unsigned inc = s;
#pragma unroll
    for (int off = 1; off < 64; off <<= 1) {
        unsigned tmp = __shfl_up(inc, off);
        if (lane >= off) inc += tmp;
    }
    unsigned run = inc - s;
#pragma unroll
    for (int k = 0; k < CH; k++) {
        int idx = c0 + k;
        if (idx < NBIN) {
            if (dumpb) dumpb[idx] = run;
            buf[idx] = run;
            run += v[k];
        }
    }
    if (dumpb && lane == 63) dumpb[NBIN] = run;  // lane 63 owns no bins: run == total
}

// ---------------- k_hist: per-block bin histogram H[blk][bin] | W transposes --------
__global__ __launch_bounds__(256) void k_hist(const float* __restrict__ W,
                                              const float* __restrict__ Wfc,
                                              unsigned short* __restrict__ WhT,
                                              unsigned short* __restrict__ WlT,
                                              unsigned short* __restrict__ WT,
                                              const int* __restrict__ edst,
                                              unsigned* __restrict__ H, int e, int ns) {
    __shared__ unsigned lh[NBIN];
    int b = blockIdx.x, t = threadIdx.x;
    if (b < ns) {
        for (int k = t; k < NBIN; k += 256) lh[k] = 0u;
        __syncthreads();
        int e0 = b * SBLK;
        int lim = e - e0; if (lim > SBLK) lim = SBLK;
        for (int k = t; k < lim; k += 256) atomicAdd(&lh[edst[e0 + k] >> 6], 1u);
        __syncthreads();
        for (int k = t; k < NBIN; k += 256) H[(size_t)b * NBIN + k] = lh[k];
    } else {
        int gid = (b - ns) * 256 + t;
        int stride = ((int)gridDim.x - ns) * 256;
        for (int i = gid; i < 128 * 128; i += stride) {
            int c = i >> 7, k = i & 127;
            float v = W[k * 128 + c];
            unsigned hi = bf16rn(v);
            WhT[c * 128 + k] = (unsigned short)hi;
            WlT[c * 128 + k] = (unsigned short)bf16rn(v - __uint_as_float(hi << 16));
        }
        for (int i = gid; i < 48 * 128; i += stride) {
            int nc = i >> 7, k = i & 127;
            WT[nc * 128 + k] = (unsigned short)((nc < 40) ? bf16rn(Wfc[k * 40 + nc]) : 0u);
        }
    }
}

// ---------------- k_scan: per-bin exclusive scan over blocks (in place) + tot -------
__global__ __launch_bounds__(256) void k_scan(unsigned* __restrict__ H,
                                              unsigned* __restrict__ tot, int ns) {
    int bin = blockIdx.x * 4 + (threadIdx.x >> 6);
    int lane = threadIdx.x & 63;
    if (bin >= NBIN) return;  // wave-uniform
    unsigned run = 0;
    for (int base = 0; base < ns; base += 64) {
        int idx = base + lane;
        unsigned v = (idx < ns) ? H[(size_t)idx * NBIN + bin] : 0u;
        unsigned inc = v;
#pragma unroll
        for (int off = 1; off < 64; off <<= 1) {
            unsigned tmp = __shfl_up(inc, off);
            if (lane >= off) inc += tmp;
        }
        if (idx < ns) H[(size_t)idx * NBIN + bin] = run + inc - v;
        run += __shfl(inc, 63);
    }
    if (lane == 0) tot[bin] = run;
}

// ---------------- k_sort: counting-sort edges by bin (no global atomics) | gemm1 ----
// bstart is computed IN-BLOCK (wave 1 scans tot) — k_binscan launch eliminated.
// Block 0 dumps bstart[0..NBIN] for k_csr. rec = (bin<<22) | (dstlow<<16) | src
__global__ __launch_bounds__(256, 4) void k_sort(const float* __restrict__ x,
                                                 const unsigned short* __restrict__ WhT,
                                                 const unsigned short* __restrict__ WlT,
                                                 unsigned short* __restrict__ hbs,
                                                 const int* __restrict__ esrc,
                                                 const int* __restrict__ edst,
                                                 const unsigned* __restrict__ H,
                                                 const unsigned* __restrict__ tot,
                                                 unsigned* __restrict__ bstart,
                                                 unsigned* __restrict__ recs,
                                                 int n, int e, int ns) {
    __shared__ unsigned bufA[NBIN];  // rank cursors
    __shared__ unsigned bufB[NBIN];  // tot -> bstart -> global chunk base for this block
    __shared__ unsigned bufC[NBIN];  // local hist -> local exclusive start
    __shared__ unsigned sbuf[SBLK];
    int b = blockIdx.x, t = threadIdx.x;

    if (b < ns) {
        int e0 = b * SBLK;
        int myE = e - e0; if (myE > SBLK) myE = SBLK;
        for (int k = t; k < NBIN; k += 256) { bufC[k] = 0u; bufA[k] = 0u; }
        __syncthreads();
        for (int k = t; k < myE; k += 256) atomicAdd(&bufC[edst[e0 + k] >> 6], 1u);
        for (int bin = t; bin < NBIN; bin += 256) bufB[bin] = tot[bin];
        __syncthreads();
        int wv = t >> 6, lane = t & 63;
        if (wv == 0) wave_scan_excl_lds(bufC, lane, 0);                       // local starts
        else if (wv == 1) wave_scan_excl_lds(bufB, lane, b == 0 ? bstart : 0); // bstart
        __syncthreads();
        for (int bin = t; bin < NBIN; bin += 256)
            bufB[bin] += H[(size_t)b * NBIN + bin];  // global chunk base
        for (int k = t; k < myE; k += 256) {
            int d = edst[e0 + k];
            int s = esrc[e0 + k];
            int bin = d >> 6;
            unsigned lr = atomicAdd(&bufA[bin], 1u);
            sbuf[bufC[bin] + lr] =
                ((unsigned)bin << 22) | ((unsigned)(d & 63) << 16) | (unsigned)s;
        }
        __syncthreads();
        for (int j = t; j < myE; j += 256) {
            unsigned rec = sbuf[j];
            unsigned bin = rec >> 22;
            recs[bufB[bin] + (unsigned)j - bufC[bin]] = rec;
        }
    } else {
        // ---- gemm1: h = x @ W_conv via 16x16x32 bf16 MFMA, hi/lo split ----
        int r0 = (b - ns) * 128;
        int wid = t >> 6, lane = t & 63;
        int mrow = lane & 15, quad = lane >> 4;
        int rb = r0 + wid * 32;

        f32x4 acc[2][8];
#pragma unroll
        for (int m = 0; m < 2; m++)
#pragma unroll
            for (int nn = 0; nn < 8; nn++) acc[m][nn] = (f32x4){0.f, 0.f, 0.f, 0.f};

#pragma unroll
        for (int ks = 0; ks < 4; ks++) {
            short8 Ah[2], Al[2];
#pragma unroll
            for (int m = 0; m < 2; m++) {
                int r = rb + m * 16 + mrow;
                if (r >= n) r = n - 1;
                const float* xp = &x[(long)r * C_DIM + ks * 32 + quad * 8];
                float4 va = *(const float4*)xp;
                float4 vb = *(const float4*)(xp + 4);
                float xv[8] = {va.x, va.y, va.z, va.w, vb.x, vb.y, vb.z, vb.w};
#pragma unroll
                for (int e8 = 0; e8 < 8; e8++) {
                    unsigned hi = bf16rn(xv[e8]);
                    Ah[m][e8] = (short)hi;
                    Al[m][e8] = (short)bf16rn(xv[e8] - __uint_as_float(hi << 16));
                }
            }
#pragma unroll
            for (int nn = 0; nn < 8; nn++) {
                int wof = (nn * 16 + mrow) * 128 + ks * 32 + quad * 8;
                short8 Bh = *(const short8*)&WhT[wof];
                short8 Bl = *(const short8*)&WlT[wof];
#pragma unroll
                for (int m = 0; m < 2; m++) {
                    acc[m][nn] = __builtin_amdgcn_mfma_f32_16x16x32_bf16(Ah[m], Bh, acc[m][nn], 0, 0, 0);
                    acc[m][nn] = __builtin_amdgcn_mfma_f32_16x16x32_bf16(Al[m], Bh, acc[m][nn], 0, 0, 0);
                    acc[m][nn] = __builtin_amdgcn_mfma_f32_16x16x32_bf16(Ah[m], Bl, acc[m][nn], 0, 0, 0);
                }
            }
        }
#pragma unroll
        for (int m = 0; m < 2; m++)
#pragma unroll
            for (int nn = 0; nn < 8; nn++) {
                int c = nn * 16 + mrow;
#pragma unroll
                for (int reg = 0; reg < 4; reg++) {
                    int r = rb + m * 16 + quad * 4 + reg;
                    if (r < n) hbs[(long)r * 128 + c] = (unsigned short)bf16rn(acc[m][nn][reg]);
                }
            }
    }
}

// ---------------- k_csr: per-bin sort by node -> CSR + rowptr + hb2 = dinv*h --------
__global__ __launch_bounds__(256) void k_csr(const unsigned* __restrict__ recs,
                                             const unsigned* __restrict__ bstart,
                                             const unsigned* __restrict__ hb,
                                             unsigned* __restrict__ hb2,
                                             unsigned short* __restrict__ csr,
                                             unsigned* __restrict__ rowptr, int n) {
    __shared__ unsigned nh[64], nstart[64], cur[64];
    __shared__ float dinvl[64];
    __shared__ unsigned short sl[4096];
    int bin = blockIdx.x, t = threadIdx.x;
    unsigned s0 = bstart[bin];
    unsigned cn = bstart[bin + 1] - s0;
    if (t < 64) { nh[t] = 0u; cur[t] = 0u; }
    __syncthreads();
    for (unsigned k = t; k < cn; k += 256) atomicAdd(&nh[(recs[s0 + k] >> 16) & 63u], 1u);
    __syncthreads();
    if (t < 64) {  // exactly wave 0, full exec
        unsigned v = nh[t];
        unsigned inc = v;
#pragma unroll
        for (int off = 1; off < 64; off <<= 1) {
            unsigned tmp = __shfl_up(inc, off);
            if (t >= off) inc += tmp;
        }
        unsigned excl = inc - v;
        nstart[t] = excl;
        rowptr[bin * 64 + t] = s0 + excl;
        dinvl[t] = rsqrtf((float)v + 1.0f);
    }
    __syncthreads();
    for (unsigned k = t; k < cn; k += 256) {
        unsigned rec = recs[s0 + k];
        unsigned nd = (rec >> 16) & 63u;
        unsigned r = atomicAdd(&cur[nd], 1u);
        unsigned idx = nstart[nd] + r;
        if (idx < 4096) sl[idx] = (unsigned short)(rec & 0xFFFFu);
        else csr[s0 + idx] = (unsigned short)(rec & 0xFFFFu);  // rare big-bin overflow
    }
    __syncthreads();
    for (unsigned k = t; k < cn && k < 4096; k += 256) csr[s0 + k] = sl[k];
    // hb2 = dinv * h for this bin's 64 rows (fused d0)
    for (int idx = t; idx < 1024; idx += 256) {
        int row = idx >> 4;
        int node = bin * 64 + row;
        if (node < n) {
            float di = dinvl[row];
            uint4 u = ((const uint4*)hb)[(size_t)node * 16 + (idx & 15)];
            uint4 o;
            o.x = pack_bf16(di * blo(u.x), di * bhi(u.x));
            o.y = pack_bf16(di * blo(u.y), di * bhi(u.y));
            o.z = pack_bf16(di * blo(u.z), di * bhi(u.z));
            o.w = pack_bf16(di * blo(u.w), di * bhi(u.w));
            ((uint4*)hb2)[(size_t)node * 16 + (idx & 15)] = o;
        }
    }
}

// -------- agg2: aggregate + bias + relu*x + LN + residual + FUSED gemm2 ----------
// 1024-thread blocks = 16 node-waves. Each wave gathers + LNs its node (proven
// round-7 structure, wave-uniform loops), writes its z row to LDS; one barrier;
// waves 0..2 each compute one 16-col MFMA tile of out = z @ W_fc + b_fc.
// zb round-trip (25.6 MB) and the gemm2 launch are gone. NO early return before
// the barrier (round-1 lesson).
__global__ __launch_bounds__(1024) void agg2(const unsigned* __restrict__ hb2,
                                             const float* __restrict__ x,
                                             const unsigned short* __restrict__ csr,
                                             const unsigned* __restrict__ rowptr,
                                             const float* __restrict__ bconv,
                                             const float* __restrict__ gamma,
                                             const float* __restrict__ beta,
                                             const unsigned short* __restrict__ WT,
                                             const float* __restrict__ bfc,
                                             float* __restrict__ out, int n) {
    __shared__ unsigned zl[16 * 65];  // 16 z rows, stride 65 u32 (bank-stagger)
    int t = threadIdx.x;
    int wv = t >> 6, lane = t & 63;
    int sub = lane & 15, grp = lane >> 4;
    int i = blockIdx.x * 16 + wv;
    bool vn = i < n;
    int ii = vn ? i : n - 1;  // clamp: invalid waves do harmless dup work, hit barrier

    unsigned rs = rowptr[ii];
    unsigned re = rowptr[ii + 1];
    int deg = (int)(re - rs);
    float di = rsqrtf((float)deg + 1.0f);

    uint4 us = *(const uint4*)(hb2 + (long)ii * 64 + sub * 4);
    float4 xa = *(const float4*)&x[(long)ii * C_DIM + sub * 8];
    float4 xb = *(const float4*)&x[(long)ii * C_DIM + sub * 8 + 4];
    int s_all = (int)csr[rs + lane];  // over-read past deg is padded/harmless

    float wself = (grp == 0) ? 1.f : 0.f;  // self term = hb2[i] (di applied after reduce)
    float acc[8];
    acc[0] = wself * blo(us.x); acc[1] = wself * bhi(us.x);
    acc[2] = wself * blo(us.y); acc[3] = wself * bhi(us.y);
    acc[4] = wself * blo(us.z); acc[5] = wself * bhi(us.z);
    acc[6] = wself * blo(us.w); acc[7] = wself * bhi(us.w);

    int nIt = (deg + 15) >> 4;  // UNIFORM trip count; 16 slots (4 per grp) per iter
    for (int it = 0; it < nIt; ++it) {
        int ss[4];
        float ww[4];
#pragma unroll
        for (int qq = 0; qq < 4; qq++) {
            int base = it * 16 + qq * 4;  // multiple of 4 -> (base>=64) uniform per wave
            int tq = base + grp;
            int sq;
            if (base >= 64) sq = (int)csr[rs + tq];  // rare fallback, wave-uniform branch
            else sq = __shfl(s_all, tq);             // full-exec bpermute
            float wq = 1.f;
            if (tq >= deg) { wq = 0.f; sq = ii; }  // predicate AFTER shuffle
            ss[qq] = sq;
            ww[qq] = wq;
        }
        uint4 u[4];
#pragma unroll
        for (int qq = 0; qq < 4; qq++) u[qq] = *(const uint4*)(hb2 + (long)ss[qq] * 64 + sub * 4);
#pragma unroll
        for (int qq = 0; qq < 4; qq++) {
            float w = ww[qq];
            acc[0] += w * blo(u[qq].x); acc[1] += w * bhi(u[qq].x);
            acc[2] += w * blo(u[qq].y); acc[3] += w * bhi(u[qq].y);
            acc[4] += w * blo(u[qq].z); acc[5] += w * bhi(u[qq].z);
            acc[6] += w * blo(u[qq].w); acc[7] += w * bhi(u[qq].w);
        }
    }

#pragma unroll
    for (int j = 0; j < 8; j++) {
        acc[j] += __shfl_xor(acc[j], 16);
        acc[j] += __shfl_xor(acc[j], 32);
    }

    float4 bca = *(const float4*)&bconv[sub * 8];
    float4 bcb = *(const float4*)&bconv[sub * 8 + 4];
    float a[8], xv[8];
    xv[0] = xa.x; xv[1] = xa.y; xv[2] = xa.z; xv[3] = xa.w;
    xv[4] = xb.x; xv[5] = xb.y; xv[6] = xb.z; xv[7] = xb.w;
    float bc[8] = {bca.x, bca.y, bca.z, bca.w, bcb.x, bcb.y, bcb.z, bcb.w};
#pragma unroll
    for (int j = 0; j < 8; j++) a[j] = fmaxf(acc[j] * di + bc[j], 0.f) * xv[j];

    float s = a[0] + a[1] + a[2] + a[3] + a[4] + a[5] + a[6] + a[7];
#pragma unroll
    for (int off = 1; off < 16; off <<= 1) s += __shfl_xor(s, off);
    float mu = s * (1.0f / 128.0f);
    float d[8], v = 0.f;
#pragma unroll
    for (int j = 0; j < 8; j++) { d[j] = a[j] - mu; v += d[j] * d[j]; }
#pragma unroll
    for (int off = 1; off < 16; off <<= 1) v += __shfl_xor(v, off);
    float inv = rsqrtf(v * (1.0f / 128.0f) + EPS);

    if (grp == 0) {
        float4 ga = *(const float4*)&gamma[sub * 8];
        float4 gb = *(const float4*)&gamma[sub * 8 + 4];
        float4 ba = *(const float4*)&beta[sub * 8];
        float4 bb = *(const float4*)&beta[sub * 8 + 4];
        float g[8] = {ga.x, ga.y, ga.z, ga.w, gb.x, gb.y, gb.z, gb.w};
        float be[8] = {ba.x, ba.y, ba.z, ba.w, bb.x, bb.y, bb.z, bb.w};
        float o[8];
#pragma unroll
        for (int j = 0; j < 8; j++) o[j] = d[j] * inv * g[j] + be[j] + xv[j];
        zl[wv * 65 + sub * 4 + 0] = pack_bf16(o[0], o[1]);
        zl[wv * 65 + sub * 4 + 1] = pack_bf16(o[2], o[3]);
        zl[wv * 65 + sub * 4 + 2] = pack_bf16(o[4], o[5]);
        zl[wv * 65 + sub * 4 + 3] = pack_bf16(o[6], o[7]);
    }
    __syncthreads();

    // fused FC: waves 0..2 each do one nt (16 output cols) for the block's 16 rows
    if (wv < 3) {
        int nt = wv;
        int mrow = lane & 15, quad = lane >> 4;
        f32x4 a2 = (f32x4){0.f, 0.f, 0.f, 0.f};
#pragma unroll
        for (int ks = 0; ks < 4; ks++) {
            union { unsigned u[4]; short8 s8; } au;
            int zi = mrow * 65 + ks * 16 + quad * 4;
            au.u[0] = zl[zi + 0];
            au.u[1] = zl[zi + 1];
            au.u[2] = zl[zi + 2];
            au.u[3] = zl[zi + 3];
            short8 B = *(const short8*)&WT[(nt * 16 + mrow) * 128 + ks * 32 + quad * 8];
            a2 = __builtin_amdgcn_mfma_f32_16x16x32_bf16(au.s8, B, a2, 0, 0, 0);
        }
        int c = nt * 16 + mrow;
        if (c < 40) {
            float bias = bfc[c];
#pragma unroll
            for (int reg = 0; reg < 4; reg++) {
                int r = blockIdx.x * 16 + quad * 4 + reg;
                if (r < n) out[(long)r * 40 + c] = a2[reg] + bias;
            }
        }
    }
}

extern "C" void kernel_launch(void* const* d_in, const int* in_sizes, int n_in,
                              void* d_out, int out_size, void* d_ws, size_t ws_size,
                              hipStream_t stream) {
    const float* x     = (const float*)d_in[0];
    const int*   ei    = (const int*)d_in[1];
    const float* Wc    = (const float*)d_in[2];
    const float* bc    = (const float*)d_in[3];
    const float* gamma = (const float*)d_in[4];
    const float* beta  = (const float*)d_in[5];
    const float* Wfc   = (const float*)d_in[6];
    const float* bfc   = (const float*)d_in[7];
    float* out = (float*)d_out;

    int N = in_sizes[0] / C_DIM;
    int E = in_sizes[1] / 2;
    const int* esrc = ei;
    const int* edst = ei + E;
    int ns = (E + SBLK - 1) / SBLK;  // 313 sort blocks
    int g1 = (N + 127) / 128;        // gemm1 blocks

    char* p = (char*)d_ws;
    auto carve = [&](size_t bytes) {
        void* q = (void*)p;
        p += (bytes + 255) & ~(size_t)255;
        return q;
    };
    unsigned* hb         = (unsigned*)carve((size_t)N * 64 * 4);        // h bf16 pairs
    unsigned* hb2        = (unsigned*)carve((size_t)N * 64 * 4);        // dinv-scaled h
    unsigned short* WT   = (unsigned short*)carve(48 * 128 * 2);
    unsigned short* WhT  = (unsigned short*)carve(128 * 128 * 2);
    unsigned short* WlT  = (unsigned short*)carve(128 * 128 * 2);
    unsigned* H          = (unsigned*)carve((size_t)ns * NBIN * 4);     // hist [blk][bin]
    unsigned* tot        = (unsigned*)carve((size_t)NBIN * 4);
    unsigned* bstart     = (unsigned*)carve((size_t)(NBIN + 1) * 4);
    unsigned* recs       = (unsigned*)carve((size_t)E * 4);             // bin-sorted recs
    unsigned* rowptr     = (unsigned*)carve((size_t)(NBIN * 64 + 1) * 4);
    unsigned short* csr  = (unsigned short*)carve((size_t)E * 2 + 256); // node-sorted srcs

    k_hist<<<ns + 64, 256, 0, stream>>>(Wc, Wfc, WhT, WlT, WT, edst, H, E, ns);
    k_scan<<<NBIN / 4, 256, 0, stream>>>(H, tot, ns);
    k_sort<<<ns + g1, 256, 0, stream>>>(x, WhT, WlT, (unsigned short*)hb, esrc, edst,
                                        H, tot, bstart, recs, N, E, ns);
    k_csr<<<NBIN, 256, 0, stream>>>(recs, bstart, hb, hb2, csr, rowptr, N);
    agg2<<<(N + 15) / 16, 1024, 0, stream>>>(hb2, x, csr, rowptr, bc, gamma, beta,
                                             WT, bfc, out, N);
}

// Round 9
// 168.793 us; speedup vs baseline: 1.0337x; 1.0337x over previous
//
#include <hip/hip_runtime.h>

#define C_DIM 128
#define EPS 1e-5f
#define NBIN 784   // bins of 64 nodes (capacity; covers N <= 50176)
#define SBLK 4096  // edges per hist/sort block -> 157 blocks; longer per-bin runs
                   // in the scatter (5.2 recs) halve write-allocate amplification

typedef __attribute__((ext_vector_type(8))) short short8;
typedef __attribute__((ext_vector_type(4))) float f32x4;

__device__ __forceinline__ unsigned bf16rn(float f) {
    unsigned u = __float_as_uint(f);
    return (u + 0x7fffu + ((u >> 16) & 1u)) >> 16;
}
__device__ __forceinline__ unsigned pack_bf16(float lo, float hi) {
    return bf16rn(lo) | (bf16rn(hi) << 16);
}
__device__ __forceinline__ float blo(unsigned u) { return __uint_as_float(u << 16); }
__device__ __forceinline__ float bhi(unsigned u) { return __uint_as_float(u & 0xffff0000u); }

// exclusive scan of LDS buf[0..NBIN) by ONE full wave (all 64 lanes must enter).
// If dumpb != 0, also writes dumpb[i]=exclusive prefix and dumpb[NBIN]=grand total.
__device__ __forceinline__ void wave_scan_excl_lds(unsigned* buf, int lane,
                                                   unsigned* dumpb) {
    const int CH = (NBIN + 63) / 64;  // 13
    unsigned v[CH];
    unsigned s = 0;
    int c0 = lane * CH;
#pragma unroll
    for (int k = 0; k < CH; k++) {
        int idx = c0 + k;
        v[k] = (idx < NBIN) ? buf[idx] : 0u;
        s += v[k];
    }
    unsigned inc = s;
#pragma unroll
    for (int off = 1; off < 64; off <<= 1) {
        unsigned tmp = __shfl_up(inc, off);
        if (lane >= off) inc += tmp;
    }
    unsigned run = inc - s;
#pragma unroll
    for (int k = 0; k < CH; k++) {
        int idx = c0 + k;
        if (idx < NBIN) {
            if (dumpb) dumpb[idx] = run;
            buf[idx] = run;
            run += v[k];
        }
    }
    if (dumpb && lane == 63) dumpb[NBIN] = run;  // lane 63 owns no bins: run == total
}

// ---------------- k_hist: per-block bin histogram H[blk][bin] | W transposes --------
__global__ __launch_bounds__(256) void k_hist(const float* __restrict__ W,
                                              const float* __restrict__ Wfc,
                                              unsigned short* __restrict__ WhT,
                                              unsigned short* __restrict__ WlT,
                                              unsigned short* __restrict__ WT,
                                              const int* __restrict__ edst,
                                              unsigned* __restrict__ H, int e, int ns) {
    __shared__ unsigned lh[NBIN];
    int b = blockIdx.x, t = threadIdx.x;
    if (b < ns) {
        for (int k = t; k < NBIN; k += 256) lh[k] = 0u;
        __syncthreads();
        int e0 = b * SBLK;
        int lim = e - e0; if (lim > SBLK) lim = SBLK;
        for (int k = t; k < lim; k += 256) atomicAdd(&lh[edst[e0 + k] >> 6], 1u);
        __syncthreads();
        for (int k = t; k < NBIN; k += 256) H[(size_t)b * NBIN + k] = lh[k];
    } else {
        int gid = (b - ns) * 256 + t;
        int stride = ((int)gridDim.x - ns) * 256;
        for (int i = gid; i < 128 * 128; i += stride) {
            int c = i >> 7, k = i & 127;
            float v = W[k * 128 + c];
            unsigned hi = bf16rn(v);
            WhT[c * 128 + k] = (unsigned short)hi;
            WlT[c * 128 + k] = (unsigned short)bf16rn(v - __uint_as_float(hi << 16));
        }
        for (int i = gid; i < 48 * 128; i += stride) {
            int nc = i >> 7, k = i & 127;
            WT[nc * 128 + k] = (unsigned short)((nc < 40) ? bf16rn(Wfc[k * 40 + nc]) : 0u);
        }
    }
}

// ---------------- k_scan: per-bin exclusive scan over blocks (in place) + tot -------
__global__ __launch_bounds__(256) void k_scan(unsigned* __restrict__ H,
                                              unsigned* __restrict__ tot, int ns) {
    int bin = blockIdx.x * 4 + (threadIdx.x >> 6);
    int lane = threadIdx.x & 63;
    if (bin >= NBIN) return;  // wave-uniform
    unsigned run = 0;
    for (int base = 0; base < ns; base += 64) {
        int idx = base + lane;
        unsigned v = (idx < ns) ? H[(size_t)idx * NBIN + bin] : 0u;
        unsigned inc = v;
#pragma unroll
        for (int off = 1; off < 64; off <<= 1) {
            unsigned tmp = __shfl_up(inc, off);
            if (lane >= off) inc += tmp;
        }
        if (idx < ns) H[(size_t)idx * NBIN + bin] = run + inc - v;
        run += __shfl(inc, 63);
    }
    if (lane == 0) tot[bin] = run;
}

// ---------------- k_sort: counting-sort edges by bin (no global atomics) | gemm1 ----
// bstart computed in-block (wave 1 scans tot); block 0 dumps bstart[0..NBIN].
// rec = (bin<<22) | (dstlow<<16) | src
__global__ __launch_bounds__(256, 4) void k_sort(const float* __restrict__ x,
                                                 const unsigned short* __restrict__ WhT,
                                                 const unsigned short* __restrict__ WlT,
                                                 unsigned short* __restrict__ hbs,
                                                 const int* __restrict__ esrc,
                                                 const int* __restrict__ edst,
                                                 const unsigned* __restrict__ H,
                                                 const unsigned* __restrict__ tot,
                                                 unsigned* __restrict__ bstart,
                                                 unsigned* __restrict__ recs,
                                                 int n, int e, int ns) {
    __shared__ unsigned bufA[NBIN];  // rank cursors
    __shared__ unsigned bufB[NBIN];  // tot -> bstart -> global chunk base for this block
    __shared__ unsigned bufC[NBIN];  // local hist -> local exclusive start
    __shared__ unsigned sbuf[SBLK];
    int b = blockIdx.x, t = threadIdx.x;

    if (b < ns) {
        int e0 = b * SBLK;
        int myE = e - e0; if (myE > SBLK) myE = SBLK;
        for (int k = t; k < NBIN; k += 256) { bufC[k] = 0u; bufA[k] = 0u; }
        __syncthreads();
        for (int k = t; k < myE; k += 256) atomicAdd(&bufC[edst[e0 + k] >> 6], 1u);
        for (int bin = t; bin < NBIN; bin += 256) bufB[bin] = tot[bin];
        __syncthreads();
        int wv = t >> 6, lane = t & 63;
        if (wv == 0) wave_scan_excl_lds(bufC, lane, 0);                        // local starts
        else if (wv == 1) wave_scan_excl_lds(bufB, lane, b == 0 ? bstart : 0); // bstart
        __syncthreads();
        for (int bin = t; bin < NBIN; bin += 256)
            bufB[bin] += H[(size_t)b * NBIN + bin];  // global chunk base
        for (int k = t; k < myE; k += 256) {
            int d = edst[e0 + k];
            int s = esrc[e0 + k];
            int bin = d >> 6;
            unsigned lr = atomicAdd(&bufA[bin], 1u);
            sbuf[bufC[bin] + lr] =
                ((unsigned)bin << 22) | ((unsigned)(d & 63) << 16) | (unsigned)s;
        }
        __syncthreads();
        for (int j = t; j < myE; j += 256) {
            unsigned rec = sbuf[j];
            unsigned bin = rec >> 22;
            recs[bufB[bin] + (unsigned)j - bufC[bin]] = rec;
        }
    } else {
        // ---- gemm1: h = x @ W_conv via 16x16x32 bf16 MFMA, hi/lo split ----
        int r0 = (b - ns) * 128;
        int wid = t >> 6, lane = t & 63;
        int mrow = lane & 15, quad = lane >> 4;
        int rb = r0 + wid * 32;

        f32x4 acc[2][8];
#pragma unroll
        for (int m = 0; m < 2; m++)
#pragma unroll
            for (int nn = 0; nn < 8; nn++) acc[m][nn] = (f32x4){0.f, 0.f, 0.f, 0.f};

#pragma unroll
        for (int ks = 0; ks < 4; ks++) {
            short8 Ah[2], Al[2];
#pragma unroll
            for (int m = 0; m < 2; m++) {
                int r = rb + m * 16 + mrow;
                if (r >= n) r = n - 1;
                const float* xp = &x[(long)r * C_DIM + ks * 32 + quad * 8];
                float4 va = *(const float4*)xp;
                float4 vb = *(const float4*)(xp + 4);
                float xv[8] = {va.x, va.y, va.z, va.w, vb.x, vb.y, vb.z, vb.w};
#pragma unroll
                for (int e8 = 0; e8 < 8; e8++) {
                    unsigned hi = bf16rn(xv[e8]);
                    Ah[m][e8] = (short)hi;
                    Al[m][e8] = (short)bf16rn(xv[e8] - __uint_as_float(hi << 16));
                }
            }
#pragma unroll
            for (int nn = 0; nn < 8; nn++) {
                int wof = (nn * 16 + mrow) * 128 + ks * 32 + quad * 8;
                short8 Bh = *(const short8*)&WhT[wof];
                short8 Bl = *(const short8*)&WlT[wof];
#pragma unroll
                for (int m = 0; m < 2; m++) {
                    acc[m][nn] = __builtin_amdgcn_mfma_f32_16x16x32_bf16(Ah[m], Bh, acc[m][nn], 0, 0, 0);
                    acc[m][nn] = __builtin_amdgcn_mfma_f32_16x16x32_bf16(Al[m], Bh, acc[m][nn], 0, 0, 0);
                    acc[m][nn] = __builtin_amdgcn_mfma_f32_16x16x32_bf16(Ah[m], Bl, acc[m][nn], 0, 0, 0);
                }
            }
        }
#pragma unroll
        for (int m = 0; m < 2; m++)
#pragma unroll
            for (int nn = 0; nn < 8; nn++) {
                int c = nn * 16 + mrow;
#pragma unroll
                for (int reg = 0; reg < 4; reg++) {
                    int r = rb + m * 16 + quad * 4 + reg;
                    if (r < n) hbs[(long)r * 128 + c] = (unsigned short)bf16rn(acc[m][nn][reg]);
                }
            }
    }
}

// ---------------- k_csr: per-bin sort by node -> CSR + rowptr + dense dinv ----------
// hb2 rescale DROPPED (was 25.6 MB of traffic): aggregate now gathers hb directly
// and weights by dinv[src] from this dense 200KB L2-resident table.
__global__ __launch_bounds__(256) void k_csr(const unsigned* __restrict__ recs,
                                             const unsigned* __restrict__ bstart,
                                             unsigned short* __restrict__ csr,
                                             unsigned* __restrict__ rowptr,
                                             float* __restrict__ dinv) {
    __shared__ unsigned nh[64], nstart[64], cur[64];
    __shared__ unsigned short sl[4096];
    int bin = blockIdx.x, t = threadIdx.x;
    unsigned s0 = bstart[bin];
    unsigned cn = bstart[bin + 1] - s0;
    if (t < 64) { nh[t] = 0u; cur[t] = 0u; }
    __syncthreads();
    for (unsigned k = t; k < cn; k += 256) atomicAdd(&nh[(recs[s0 + k] >> 16) & 63u], 1u);
    __syncthreads();
    if (t < 64) {  // exactly wave 0, full exec
        unsigned v = nh[t];
        unsigned inc = v;
#pragma unroll
        for (int off = 1; off < 64; off <<= 1) {
            unsigned tmp = __shfl_up(inc, off);
            if (t >= off) inc += tmp;
        }
        unsigned excl = inc - v;
        nstart[t] = excl;
        rowptr[bin * 64 + t] = s0 + excl;
        dinv[bin * 64 + t] = rsqrtf((float)v + 1.0f);
    }
    __syncthreads();
    for (unsigned k = t; k < cn; k += 256) {
        unsigned rec = recs[s0 + k];
        unsigned nd = (rec >> 16) & 63u;
        unsigned r = atomicAdd(&cur[nd], 1u);
        unsigned idx = nstart[nd] + r;
        if (idx < 4096) sl[idx] = (unsigned short)(rec & 0xFFFFu);
        else csr[s0 + idx] = (unsigned short)(rec & 0xFFFFu);  // rare big-bin overflow
    }
    __syncthreads();
    for (unsigned k = t; k < cn && k < 4096; k += 256) csr[s0 + k] = sl[k];
}

// ---------------- fused aggregate + bias + relu*x + LN + residual (CSR) --------
// One wave per node, 4-wave blocks, NO inter-wave barrier (round-8 convoy lesson).
// Weights: dinv[src] gathered once per lane (dense table), shuffled with src ids.
// Gather loop WAVE-UNIFORM (round-1 lesson: __shfl from inactive lane returns 0).
__global__ __launch_bounds__(256) void aggregate(const unsigned* __restrict__ hb,
                                                 const float* __restrict__ x,
                                                 const unsigned short* __restrict__ csr,
                                                 const unsigned* __restrict__ rowptr,
                                                 const float* __restrict__ dinv,
                                                 const float* __restrict__ bconv,
                                                 const float* __restrict__ gamma,
                                                 const float* __restrict__ beta,
                                                 unsigned* __restrict__ zb, int n) {
    int wid = (blockIdx.x * blockDim.x + threadIdx.x) >> 6;
    if (wid >= n) return;  // wave-uniform
    int lane = threadIdx.x & 63;
    int sub = lane & 15, grp = lane >> 4;
    int i = wid;

    unsigned rs = rowptr[i];
    unsigned re = rowptr[i + 1];
    int deg = (int)(re - rs);
    float di = rsqrtf((float)deg + 1.0f);

    // hoist independent loads (slot table: src id + weight per lane)
    uint4 us = *(const uint4*)(hb + (long)i * 64 + sub * 4);
    float4 xa = *(const float4*)&x[(long)i * C_DIM + sub * 8];
    float4 xb = *(const float4*)&x[(long)i * C_DIM + sub * 8 + 4];
    int s_all = (int)csr[rs + lane];  // over-read past deg: pad'd, predicated later
    float w_all = dinv[s_all];        // dense table gather (value unused if invalid)

    float wself = (grp == 0) ? di : 0.f;  // self: di*h[i], then *di after reduce = di^2 h
    float acc[8];
    acc[0] = wself * blo(us.x); acc[1] = wself * bhi(us.x);
    acc[2] = wself * blo(us.y); acc[3] = wself * bhi(us.y);
    acc[4] = wself * blo(us.z); acc[5] = wself * bhi(us.z);
    acc[6] = wself * blo(us.w); acc[7] = wself * bhi(us.w);

    int nIt = (deg + 15) >> 4;  // UNIFORM trip count; 16 slots (4 per grp) per iter
    for (int it = 0; it < nIt; ++it) {
        int ss[4];
        float ww[4];
#pragma unroll
        for (int qq = 0; qq < 4; qq++) {
            int base = it * 16 + qq * 4;  // multiple of 4 -> (base>=64) uniform per wave
            int tq = base + grp;
            int sq;
            float wq;
            if (base >= 64) {             // rare deg>64 fallback, wave-uniform branch
                sq = (int)csr[rs + tq];
                wq = dinv[sq];
            } else {
                sq = __shfl(s_all, tq);   // full-exec bpermute
                wq = __shfl(w_all, tq);
            }
            if (tq >= deg) { wq = 0.f; sq = i; }  // predicate AFTER shuffle
            ss[qq] = sq;
            ww[qq] = wq;
        }
        uint4 u[4];
#pragma unroll
        for (int qq = 0; qq < 4; qq++) u[qq] = *(const uint4*)(hb + (long)ss[qq] * 64 + sub * 4);
#pragma unroll
        for (int qq = 0; qq < 4; qq++) {
            float w = ww[qq];
            acc[0] += w * blo(u[qq].x); acc[1] += w * bhi(u[qq].x);
            acc[2] += w * blo(u[qq].y); acc[3] += w * bhi(u[qq].y);
            acc[4] += w * blo(u[qq].z); acc[5] += w * bhi(u[qq].z);
            acc[6] += w * blo(u[qq].w); acc[7] += w * bhi(u[qq].w);
        }
    }

#pragma unroll
    for (int j = 0; j < 8; j++) {
        acc[j] += __shfl_xor(acc[j], 16);
        acc[j] += __shfl_xor(acc[j], 32);
    }

    float4 bca = *(const float4*)&bconv[sub * 8];
    float4 bcb = *(const float4*)&bconv[sub * 8 + 4];
    float a[8], xv[8];
    xv[0] = xa.x; xv[1] = xa.y; xv[2] = xa.z; xv[3] = xa.w;
    xv[4] = xb.x; xv[5] = xb.y; xv[6] = xb.z; xv[7] = xb.w;
    float bc[8] = {bca.x, bca.y, bca.z, bca.w, bcb.x, bcb.y, bcb.z, bcb.w};
#pragma unroll
    for (int j = 0; j < 8; j++) a[j] = fmaxf(acc[j] * di + bc[j], 0.f) * xv[j];

    float s = a[0] + a[1] + a[2] + a[3] + a[4] + a[5] + a[6] + a[7];
#pragma unroll
    for (int off = 1; off < 16; off <<= 1) s += __shfl_xor(s, off);
    float mu = s * (1.0f / 128.0f);
    float d[8], v = 0.f;
#pragma unroll
    for (int j = 0; j < 8; j++) { d[j] = a[j] - mu; v += d[j] * d[j]; }
#pragma unroll
    for (int off = 1; off < 16; off <<= 1) v += __shfl_xor(v, off);
    float inv = rsqrtf(v * (1.0f / 128.0f) + EPS);

    if (grp == 0) {
        float4 ga = *(const float4*)&gamma[sub * 8];
        float4 gb = *(const float4*)&gamma[sub * 8 + 4];
        float4 ba = *(const float4*)&beta[sub * 8];
        float4 bb = *(const float4*)&beta[sub * 8 + 4];
        float g[8] = {ga.x, ga.y, ga.z, ga.w, gb.x, gb.y, gb.z, gb.w};
        float be[8] = {ba.x, ba.y, ba.z, ba.w, bb.x, bb.y, bb.z, bb.w};
        float o[8];
#pragma unroll
        for (int j = 0; j < 8; j++) o[j] = d[j] * inv * g[j] + be[j] + xv[j];
        uint4 p;
        p.x = pack_bf16(o[0], o[1]);
        p.y = pack_bf16(o[2], o[3]);
        p.z = pack_bf16(o[4], o[5]);
        p.w = pack_bf16(o[6], o[7]);
        *(uint4*)(zb + (long)i * 64 + sub * 4) = p;
    }
}

// ---------------- GEMM2: out = z @ W_fc + b_fc via bf16 MFMA, no LDS ----------------
__global__ __launch_bounds__(256) void gemm2(const unsigned short* __restrict__ zb,
                                             const unsigned short* __restrict__ WT,
                                             const float* __restrict__ bfc,
                                             float* __restrict__ out, int n) {
    int t = threadIdx.x;
    int w = t >> 6, lane = t & 63;
    int r0 = blockIdx.x * 64 + w * 16;
    if (r0 >= n) return;  // wave-uniform
    int mrow = lane & 15;
    int quad = lane >> 4;
    f32x4 acc[3];
#pragma unroll
    for (int nt = 0; nt < 3; nt++) acc[nt] = (f32x4){0.f, 0.f, 0.f, 0.f};
#pragma unroll
    for (int ks = 0; ks < 4; ks++) {
        int r = r0 + mrow;
        if (r >= n) r = n - 1;  // clamp (stores are guarded)
        short8 A = *(const short8*)&zb[(long)r * 128 + ks * 32 + quad * 8];
        short8 B[3];
#pragma unroll
        for (int nt = 0; nt < 3; nt++)
            B[nt] = *(const short8*)&WT[(nt * 16 + mrow) * 128 + ks * 32 + quad * 8];
#pragma unroll
        for (int nt = 0; nt < 3; nt++)
            acc[nt] = __builtin_amdgcn_mfma_f32_16x16x32_bf16(A, B[nt], acc[nt], 0, 0, 0);
    }
#pragma unroll
    for (int nt = 0; nt < 3; nt++) {
        int c = nt * 16 + mrow;
        if (c < 40) {
            float bias = bfc[c];
#pragma unroll
            for (int reg = 0; reg < 4; reg++) {
                int r = r0 + quad * 4 + reg;
                if (r < n) out[(long)r * 40 + c] = acc[nt][reg] + bias;
            }
        }
    }
}

extern "C" void kernel_launch(void* const* d_in, const int* in_sizes, int n_in,
                              void* d_out, int out_size, void* d_ws, size_t ws_size,
                              hipStream_t stream) {
    const float* x     = (const float*)d_in[0];
    const int*   ei    = (const int*)d_in[1];
    const float* Wc    = (const float*)d_in[2];
    const float* bc    = (const float*)d_in[3];
    const float* gamma = (const float*)d_in[4];
    const float* beta  = (const float*)d_in[5];
    const float* Wfc   = (const float*)d_in[6];
    const float* bfc   = (const float*)d_in[7];
    float* out = (float*)d_out;

    int N = in_sizes[0] / C_DIM;
    int E = in_sizes[1] / 2;
    const int* esrc = ei;
    const int* edst = ei + E;
    int ns = (E + SBLK - 1) / SBLK;  // 157 sort blocks
    int g1 = (N + 127) / 128;        // gemm1 blocks

    char* p = (char*)d_ws;
    auto carve = [&](size_t bytes) {
        void* q = (void*)p;
        p += (bytes + 255) & ~(size_t)255;
        return q;
    };
    unsigned* hb         = (unsigned*)carve((size_t)N * 64 * 4);        // h bf16 pairs (LIVE through aggregate)
    unsigned* zb         = (unsigned*)carve((size_t)N * 64 * 4);        // z bf16 pairs (NOT aliased: hb read during aggregate)
    unsigned short* WT   = (unsigned short*)carve(48 * 128 * 2);
    unsigned short* WhT  = (unsigned short*)carve(128 * 128 * 2);
    unsigned short* WlT  = (unsigned short*)carve(128 * 128 * 2);
    unsigned* H          = (unsigned*)carve((size_t)ns * NBIN * 4);     // hist [blk][bin]
    unsigned* tot        = (unsigned*)carve((size_t)NBIN * 4);
    unsigned* bstart     = (unsigned*)carve((size_t)(NBIN + 1) * 4);
    unsigned* recs       = (unsigned*)carve((size_t)E * 4);             // bin-sorted recs
    unsigned* rowptr     = (unsigned*)carve((size_t)(NBIN * 64 + 1) * 4);
    unsigned short* csr  = (unsigned short*)carve((size_t)E * 2 + 256); // node-sorted srcs
    float* dinv          = (float*)carve(65536 * 4);  // padded to ushort range: garbage
                                                      // csr over-reads index safely

    k_hist<<<ns + 64, 256, 0, stream>>>(Wc, Wfc, WhT, WlT, WT, edst, H, E, ns);
    k_scan<<<NBIN / 4, 256, 0, stream>>>(H, tot, ns);
    k_sort<<<ns + g1, 256, 0, stream>>>(x, WhT, WlT, (unsigned short*)hb, esrc, edst,
                                        H, tot, bstart, recs, N, E, ns);
    k_csr<<<NBIN, 256, 0, stream>>>(recs, bstart, csr, rowptr, dinv);
    aggregate<<<((size_t)N * 64 + 255) / 256, 256, 0, stream>>>(
        hb, x, csr, rowptr, dinv, bc, gamma, beta, zb, N);
    gemm2<<<(N + 63) / 64, 256, 0, stream>>>((const unsigned short*)zb, WT, bfc, out, N);
}